// Round 1
// baseline (35.783 us; speedup 1.0000x reference)
//
#include <hip/hip_runtime.h>
#include <math.h>

#define TPB 512

// tanh-approx gelu (matches jax.nn.gelu approximate=True):
// gelu(y) = y * sigmoid(2*sqrt(2/pi)*(y + 0.044715 y^3))
// exp2-based: w = y*(C1 + C2*y^2), C1 = 2*sqrt(2/pi)*log2(e), C2 = C1*0.044715
__device__ __forceinline__ float fast_gelu(float y) {
    const float C1 = 2.3022082f;
    const float C2 = 0.10294324f;
    float y2 = y * y;
    float w  = y * fmaf(C2, y2, C1);
    float E  = __builtin_amdgcn_exp2f(w);
    float r  = __builtin_amdgcn_rcpf(1.0f + E);   // sigmoid(-w)
    return fmaf(-y, r, y);                        // y*(1-r) = y*sigmoid(w)
}

__global__ __launch_bounds__(TPB) void smn_fused(
    const float* __restrict__ x, const float* __restrict__ x_size,
    const float* __restrict__ w1a, const float* __restrict__ b1a,
    const float* __restrict__ w1b, const float* __restrict__ b1b,
    const float* __restrict__ w2a, const float* __restrict__ b2a,
    const float* __restrict__ w2b, const float* __restrict__ b2b,
    const float* __restrict__ w3, const float* __restrict__ b3,
    float* __restrict__ out)
{
    // N=32, D=64, H=2, one (b1,b2) set per block
    __shared__ __align__(16) float xs[2048];      // normalized+masked x [32][64]
    __shared__ __align__(16) float xm[2048];      // x_mlp1 [32][64]
    // big: phase-overlapped region
    //   P1a-P1b: h1[32][128]              = big[0..4095]
    //   P2-P3:   A1bT[128][33]            = big[0..4223]   (A1 + b2a, transposed, padded)
    //            A2T [128][33]            = big[4224..8447]
    //   P3-P4:   tmat[32][32]             = big[8448..9471]
    __shared__ __align__(16) float big[9472];
    __shared__ float wcs[128];
    __shared__ float maskv[32];
    __shared__ float redbuf[16];

    const int tid = threadIdx.x;
    const int set = blockIdx.x;
    const float* xg = x + set * 2048;

    // ---- P0: load x (4 floats/thread, one row per 16 threads), mask, mean ----
    float4 v = reinterpret_cast<const float4*>(xg)[tid];
    if (tid < 128) wcs[tid] = w2b[2*tid] * w3[0] + w2b[2*tid+1] * w3[1];
    {
        bool nz = (v.x != 0.f) || (v.y != 0.f) || (v.z != 0.f) || (v.w != 0.f);
        unsigned long long bal = __ballot(nz);
        if ((tid & 15) == 0) {
            int lane = tid & 63;
            maskv[tid >> 4] = ((bal >> (lane & 48)) & 0xFFFFull) ? 1.0f : 0.0f;
        }
    }
    float s = (v.x + v.y) + (v.z + v.w);
    #pragma unroll
    for (int o = 32; o > 0; o >>= 1) s += __shfl_xor(s, o, 64);
    if ((tid & 63) == 0) redbuf[tid >> 6] = s;
    __syncthreads();

    const float denom = x_size[set >> 4] * 64.0f;
    float tot = 0.f;
    #pragma unroll
    for (int w8 = 0; w8 < 8; ++w8) tot += redbuf[w8];
    const float mean = tot / denom;
    const float mr0 = maskv[tid >> 4];
    float d0 = v.x - mean, d1 = v.y - mean, d2 = v.z - mean, d3 = v.w - mean;
    float ss = ((d0*d0 + d1*d1) + (d2*d2 + d3*d3)) * mr0;
    #pragma unroll
    for (int o = 32; o > 0; o >>= 1) ss += __shfl_xor(ss, o, 64);
    if ((tid & 63) == 0) redbuf[8 + (tid >> 6)] = ss;
    __syncthreads();

    float ssum = 0.f;
    #pragma unroll
    for (int w8 = 0; w8 < 8; ++w8) ssum += redbuf[8 + w8];
    const float stdv = sqrtf(ssum / denom);
    const float inv = mr0 / (stdv + 1e-8f);
    float4 xnv;
    xnv.x = d0 * inv; xnv.y = d1 * inv; xnv.z = d2 * inv; xnv.w = d3 * inv;
    reinterpret_cast<float4*>(xs)[tid] = xnv;
    __syncthreads();

    // ---- P1a: h1[r][hh] = gelu(xs @ w1a + b1a)   [32][128] ----
    {
        const int hh = tid & 127;
        const int rg = tid >> 7;          // 0..3
        const float bias = b1a[hh];
        for (int rr = 0; rr < 8; ++rr) {
            const int r = rg + (rr << 2);
            float acc = bias;
            const float4* xr = reinterpret_cast<const float4*>(xs + r*64);
            #pragma unroll
            for (int kc = 0; kc < 16; ++kc) {
                float4 xv = xr[kc];
                const float* wp = w1a + kc*4*128 + hh;
                acc = fmaf(xv.x, wp[0],   acc);
                acc = fmaf(xv.y, wp[128], acc);
                acc = fmaf(xv.z, wp[256], acc);
                acc = fmaf(xv.w, wp[384], acc);
            }
            big[r*128 + hh] = fast_gelu(acc);
        }
    }
    __syncthreads();

    // ---- P1b: xm[r][d] = (h1 @ w1b + b1b) * mask[r]   [32][64] ----
    {
        const int d = tid & 63;
        const int rg = tid >> 6;          // 0..7
        const float bias = b1b[d];
        for (int rr = 0; rr < 4; ++rr) {
            const int r = rg + (rr << 3);
            float acc = bias;
            const float4* hr = reinterpret_cast<const float4*>(big + r*128);
            #pragma unroll
            for (int hc = 0; hc < 32; ++hc) {
                float4 hv = hr[hc];
                const float* wp = w1b + hc*4*64 + d;
                acc = fmaf(hv.x, wp[0],   acc);
                acc = fmaf(hv.y, wp[64],  acc);
                acc = fmaf(hv.z, wp[128], acc);
                acc = fmaf(hv.w, wp[192], acc);
            }
            xm[r*64 + d] = acc * maskv[r];
        }
    }
    __syncthreads();

    // ---- P2: A1bT[hh][r] = (xm @ w2a)[r][hh] + b2a[hh];  A2T[hh][r] = (xs @ w2a)[r][hh] ----
    {
        const int hh = tid & 127;
        const int rg = tid >> 7;          // 0..3
        const float bias = b2a[hh];
        for (int rr = 0; rr < 8; ++rr) {
            const int r = rg + (rr << 2);
            float a1 = bias, a2 = 0.f;
            const float4* mrp = reinterpret_cast<const float4*>(xm + r*64);
            const float4* srp = reinterpret_cast<const float4*>(xs + r*64);
            #pragma unroll
            for (int kc = 0; kc < 16; ++kc) {
                float4 mv = mrp[kc];
                float4 sv = srp[kc];
                const float* wp = w2a + kc*4*128 + hh;
                float w0 = wp[0], w1 = wp[128], w2v = wp[256], w3v = wp[384];
                a1 = fmaf(mv.x, w0, a1);  a2 = fmaf(sv.x, w0, a2);
                a1 = fmaf(mv.y, w1, a1);  a2 = fmaf(sv.y, w1, a2);
                a1 = fmaf(mv.z, w2v, a1); a2 = fmaf(sv.z, w2v, a2);
                a1 = fmaf(mv.w, w3v, a1); a2 = fmaf(sv.w, w3v, a2);
            }
            big[hh*33 + r] = a1;
            big[4224 + hh*33 + r] = a2;
        }
    }
    __syncthreads();

    // ---- P3: tmat[i][j] = sum_hh gelu(A1b[i][hh]-A2[j][hh]) * wc[hh] + c0 ----
    {
        const int j  = tid & 31;
        const int ig = tid >> 5;          // 0..15
        const float c0 = b2b[0]*w3[0] + b2b[1]*w3[1];
        float acc0 = c0, acc1 = c0;
        #pragma unroll 4
        for (int hh = 0; hh < 128; ++hh) {
            float a2  = big[4224 + hh*33 + j];
            float a1x = big[hh*33 + ig];
            float a1y = big[hh*33 + ig + 16];
            float wv  = wcs[hh];
            acc0 = fmaf(fast_gelu(a1x - a2), wv, acc0);
            acc1 = fmaf(fast_gelu(a1y - a2), wv, acc1);
        }
        big[8448 + ig*32 + j]        = acc0;
        big[8448 + (ig + 16)*32 + j] = acc1;
    }
    __syncthreads();

    // ---- P4: out[j][d] = (sum_i t[i][j]*xm[i][d] + b3 + x_orig[j][d]) * mask[j] ----
    {
        const int d  = tid & 63;
        const int jg = tid >> 6;          // 0..7
        const float bb = b3[0];
        for (int rr = 0; rr < 4; ++rr) {
            const int j = jg + (rr << 3);
            float acc = 0.f;
            #pragma unroll
            for (int i = 0; i < 32; ++i)
                acc = fmaf(big[8448 + i*32 + j], xm[i*64 + d], acc);
            float o = (acc + bb + xg[j*64 + d]) * maskv[j];
            out[set*2048 + j*64 + d] = o;
        }
    }
}

extern "C" void kernel_launch(void* const* d_in, const int* in_sizes, int n_in,
                              void* d_out, int out_size, void* d_ws, size_t ws_size,
                              hipStream_t stream) {
    const float* x   = (const float*)d_in[0];
    const float* xsz = (const float*)d_in[1];
    const float* w1a = (const float*)d_in[2];
    const float* b1a = (const float*)d_in[3];
    const float* w1b = (const float*)d_in[4];
    const float* b1b = (const float*)d_in[5];
    const float* w2a = (const float*)d_in[6];
    const float* b2a = (const float*)d_in[7];
    const float* w2b = (const float*)d_in[8];
    const float* b2b = (const float*)d_in[9];
    const float* w3  = (const float*)d_in[10];
    const float* b3  = (const float*)d_in[11];
    float* out = (float*)d_out;
    hipLaunchKernelGGL(smn_fused, dim3(256), dim3(TPB), 0, stream,
                       x, xsz, w1a, b1a, w1b, b1b, w2a, b2a, w2b, b2b, w3, b3, out);
}